// Round 9
// baseline (33144.244 us; speedup 1.0000x reference)
//
#include <hip/hip_runtime.h>

#define T_STEPS 1024
#define BSZ 256
#define HD 256
#define OUTC 64

// ---------------- ws layout (float offsets) ----------------
static const size_t OFF_SUM  = 0;        // [256][256] f32  (Sum_t outs)
static const size_t OFF_FLAG = 65536;    // int flag (x is int64?)
static const size_t OFF_WP   = 65792;    // 3 x [128][256] float4 packed weights
// total ~460K floats ~= 1.8MB

// x-dtype detector: if x is int64, all sampled high 32-bit words are zero.
__global__ void detect_x(const int* __restrict__ x, float* __restrict__ ws) {
    __shared__ int nonzero;
    if (threadIdx.x == 0) nonzero = 0;
    __syncthreads();
    if (x[2 * threadIdx.x + 1] != 0) nonzero = 1;   // benign same-value race
    __syncthreads();
    if (threadIdx.x == 0) *(int*)(ws + OFF_FLAG) = (nonzero == 0) ? 1 : 0;
}

// Pack weights as float4 per (k-quad, column): Wp[z][q][j] = {W_z[j][4q+c]}.
// Values identical to the row-major source -> FMA chains stay bit-identical;
// consumer does one dwordx4 per 4 consecutive k instead of 4 strided dwords.
__global__ void prep_pack(const float* __restrict__ Wi2h,
                          const float* __restrict__ Wi2o,
                          const float* __restrict__ Wo2o,
                          float* __restrict__ ws) {
    const int q = blockIdx.x;            // 0..127 (k quad)
    const int z = blockIdx.y;            // 0..2
    const int j = threadIdx.x;           // 0..255 (column)
    const float* src = (z == 0) ? Wi2h : (z == 1) ? Wi2o : Wo2o;
    const float4 v = *reinterpret_cast<const float4*>(src + (size_t)j * 512 + 4 * q);
    reinterpret_cast<float4*>(ws + OFF_WP)[((size_t)z * 128 + q) * 256 + j] = v;
}

// Bit-faithful f32 scan, float4-packed-weight version. Each block owns 4
// batch rows for all 1024 steps; thread (s,j) handles rows 2s,2s+1, column j.
// Chains: k-ascending sequential fmaf, e-part then h-part — identical order
// and values to the validated R7/R8 kernels; only load width changed.
__global__ __launch_bounds__(512) void scan_all(
    const int* __restrict__ x, const float* __restrict__ emb,
    const float* __restrict__ bih, const float* __restrict__ bio,
    const float* __restrict__ boo, float* __restrict__ ws) {
    const int tid = threadIdx.x;
    const int j = tid & 255;          // output column
    const int s = tid >> 8;           // slot 0..1 -> rows bl = 2s, 2s+1
    const int bl0 = s * 2, bl1 = s * 2 + 1;
    const int b0 = blockIdx.x * 4;
    const int mode64 = *(const int*)(ws + OFF_FLAG);

    const float4* __restrict__ Wh4  = reinterpret_cast<const float4*>(ws + OFF_WP) + j;
    const float4* __restrict__ Wio4 = Wh4 + (size_t)128 * 256;
    const float4* __restrict__ Woo4 = Wh4 + (size_t)256 * 256;

    __shared__ __align__(16) float eL[4][256];
    __shared__ __align__(16) float hPing[4][256];
    __shared__ __align__(16) float hPong[4][256];
    __shared__ __align__(16) float oL[4][256];
    __shared__ float sumL[4][256];
    __shared__ int tokL[4];

    hPing[bl0][j] = 0.f; hPing[bl1][j] = 0.f;   // h_0 = 0
    sumL[bl0][j] = 0.f;  sumL[bl1][j] = 0.f;
    __syncthreads();

    const float bih_j = bih[j], bio_j = bio[j], boo_j = boo[j];

    for (int t = 0; t < T_STEPS; ++t) {
        if (tid < 4) {
            const int idx = t * BSZ + b0 + tid;
            tokL[tid] = mode64 ? x[2 * idx] : x[idx];
        }
        __syncthreads();
        eL[bl0][j] = emb[(size_t)tokL[bl0] * HD + j];
        eL[bl1][j] = emb[(size_t)tokL[bl1] * HD + j];
        __syncthreads();

        const float (*hO)[256] = (t & 1) ? hPong : hPing;
        float (*hN)[256]       = (t & 1) ? hPing : hPong;
        const float4* __restrict__ e0p = (const float4*)eL[bl0];
        const float4* __restrict__ e1p = (const float4*)eL[bl1];
        const float4* __restrict__ h0p = (const float4*)hO[bl0];
        const float4* __restrict__ h1p = (const float4*)hO[bl1];

        // ---- h_new[j], o[j]: FMA chain over k = 0..511 (e part then h part)
        float ah0 = 0.f, ah1 = 0.f, ao0 = 0.f, ao1 = 0.f;
        #pragma unroll 8
        for (int q = 0; q < 64; ++q) {              // k = 0..255 : e part
            const float4 wh = Wh4[(size_t)q * 256];
            const float4 wo = Wio4[(size_t)q * 256];
            const float4 e0 = e0p[q], e1 = e1p[q];
            const float* wha = (const float*)&wh;
            const float* woa = (const float*)&wo;
            const float* e0a = (const float*)&e0;
            const float* e1a = (const float*)&e1;
            #pragma unroll
            for (int c = 0; c < 4; ++c) {
                ah0 = fmaf(e0a[c], wha[c], ah0); ah1 = fmaf(e1a[c], wha[c], ah1);
                ao0 = fmaf(e0a[c], woa[c], ao0); ao1 = fmaf(e1a[c], woa[c], ao1);
            }
        }
        #pragma unroll 8
        for (int q = 64; q < 128; ++q) {            // k = 256..511 : h part
            const float4 wh = Wh4[(size_t)q * 256];
            const float4 wo = Wio4[(size_t)q * 256];
            const float4 h0 = h0p[q - 64], h1 = h1p[q - 64];
            const float* wha = (const float*)&wh;
            const float* woa = (const float*)&wo;
            const float* h0a = (const float*)&h0;
            const float* h1a = (const float*)&h1;
            #pragma unroll
            for (int c = 0; c < 4; ++c) {
                ah0 = fmaf(h0a[c], wha[c], ah0); ah1 = fmaf(h1a[c], wha[c], ah1);
                ao0 = fmaf(h0a[c], woa[c], ao0); ao1 = fmaf(h1a[c], woa[c], ao1);
            }
        }
        const float hn0 = ah0 + bih_j, hn1 = ah1 + bih_j;  // + b_i2h
        const float on0 = ao0 + bio_j, on1 = ao1 + bio_j;  // + b_i2o
        hN[bl0][j] = hn0; hN[bl1][j] = hn1;
        oL[bl0][j] = on0; oL[bl1][j] = on1;
        __syncthreads();

        // ---- out[j]: FMA chain over k = 0..511 (h_new part then o part)
        const float4* __restrict__ n0p = (const float4*)hN[bl0];
        const float4* __restrict__ n1p = (const float4*)hN[bl1];
        const float4* __restrict__ o0p = (const float4*)oL[bl0];
        const float4* __restrict__ o1p = (const float4*)oL[bl1];
        float ac0 = 0.f, ac1 = 0.f;
        #pragma unroll 8
        for (int q = 0; q < 64; ++q) {              // h_new part
            const float4 w = Woo4[(size_t)q * 256];
            const float4 v0 = n0p[q], v1 = n1p[q];
            const float* wa = (const float*)&w;
            const float* v0a = (const float*)&v0;
            const float* v1a = (const float*)&v1;
            #pragma unroll
            for (int c = 0; c < 4; ++c) {
                ac0 = fmaf(v0a[c], wa[c], ac0);
                ac1 = fmaf(v1a[c], wa[c], ac1);
            }
        }
        #pragma unroll 8
        for (int q = 64; q < 128; ++q) {            // o part
            const float4 w = Woo4[(size_t)q * 256];
            const float4 v0 = o0p[q - 64], v1 = o1p[q - 64];
            const float* wa = (const float*)&w;
            const float* v0a = (const float*)&v0;
            const float* v1a = (const float*)&v1;
            #pragma unroll
            for (int c = 0; c < 4; ++c) {
                ac0 = fmaf(v0a[c], wa[c], ac0);
                ac1 = fmaf(v1a[c], wa[c], ac1);
            }
        }
        // Sum_t accumulation, t-ascending, f32 (np.mean axis-0 order)
        sumL[bl0][j] += (ac0 + boo_j);
        sumL[bl1][j] += (ac1 + boo_j);
        __syncthreads();
    }

    ws[OFF_SUM + (size_t)(b0 + bl0) * 256 + j] = sumL[bl0][j];
    ws[OFF_SUM + (size_t)(b0 + bl1) * 256 + j] = sumL[bl1][j];
}

// encoded = Sum/1024 (exact); logits = seq-k FMA + b_pred; log_softmax with
// f64-CR exp/log; first-index argmax over f32 lp.
__global__ __launch_bounds__(64) void final_k(
    const float* __restrict__ Wpred, const float* __restrict__ bpred,
    const float* __restrict__ ws, float* __restrict__ out) {
    const int b = blockIdx.x, o = threadIdx.x;
    __shared__ float enc[256];
    __shared__ float exs[64];
    __shared__ float s32s;

    #pragma unroll
    for (int u = 0; u < 4; ++u)
        enc[o * 4 + u] = ws[OFF_SUM + (size_t)b * 256 + o * 4 + u] * (1.0f / 1024.0f);
    __syncthreads();

    float acc = 0.f;
    for (int e = 0; e < 256; ++e)
        acc = fmaf(enc[e], Wpred[(size_t)o * 256 + e], acc);
    acc += bpred[o];                      // logits[b][o], f32

    float m = acc;
    #pragma unroll
    for (int d = 1; d < 64; d <<= 1) m = fmaxf(m, __shfl_xor(m, d));
    const float sh = acc - m;
    const float ex = (float)exp((double)sh);
    exs[o] = ex;
    __syncthreads();
    if (o == 0) {
        double sd = 0.0;
        for (int i = 0; i < 64; ++i) sd += (double)exs[i];
        s32s = (float)sd;
    }
    __syncthreads();
    const float log_s = (float)log((double)s32s);
    const float lp = sh - log_s;
    const float pr = (float)exp((double)lp);

    float av = lp; int ai = o;
    #pragma unroll
    for (int d = 1; d < 64; d <<= 1) {
        const float ov = __shfl_xor(av, d);
        const int oi = __shfl_xor(ai, d);
        if (ov > av || (ov == av && oi < ai)) { av = ov; ai = oi; }
    }

    out[BSZ + (size_t)b * OUTC + o] = lp;              // logprobs
    out[BSZ + 16384 + (size_t)b * OUTC + o] = pr;      // probs
    if (o == 0) out[b] = (float)ai;                    // preds
}

// ---------------- host ----------------
extern "C" void kernel_launch(void* const* d_in, const int* in_sizes, int n_in,
                              void* d_out, int out_size, void* d_ws, size_t ws_size,
                              hipStream_t stream) {
    const int*   x     = (const int*)d_in[0];
    const float* emb   = (const float*)d_in[1];
    const float* Wi2h  = (const float*)d_in[2];
    const float* b_ih  = (const float*)d_in[3];
    const float* Wi2o  = (const float*)d_in[4];
    const float* b_io  = (const float*)d_in[5];
    const float* Wo2o  = (const float*)d_in[6];
    const float* b_oo  = (const float*)d_in[7];
    const float* Wpred = (const float*)d_in[8];
    const float* b_p   = (const float*)d_in[9];
    float* ws  = (float*)d_ws;
    float* out = (float*)d_out;

    detect_x<<<1, 256, 0, stream>>>(x, ws);
    prep_pack<<<dim3(128, 3), 256, 0, stream>>>(Wi2h, Wi2o, Wo2o, ws);
    scan_all<<<dim3(64), 512, 0, stream>>>(x, emb, b_ih, b_io, b_oo, ws);
    final_k<<<dim3(256), 64, 0, stream>>>(Wpred, b_p, ws, out);
}

// Round 10
// 19199.272 us; speedup vs baseline: 1.7263x; 1.7263x over previous
//
#include <hip/hip_runtime.h>

#define T_STEPS 1024
#define BSZ 256
#define HD 256
#define OUTC 64

// ---------------- ws layout (float offsets) ----------------
static const size_t OFF_SUM  = 0;        // [256][256] f32  (Sum_t outs)
static const size_t OFF_FLAG = 65536;    // int flag (x is int64?)
static const size_t OFF_WP   = 65792;    // 3 x [128][256] float4 packed weights

// x-dtype detector: if x is int64, all sampled high 32-bit words are zero.
__global__ void detect_x(const int* __restrict__ x, float* __restrict__ ws) {
    __shared__ int nonzero;
    if (threadIdx.x == 0) nonzero = 0;
    __syncthreads();
    if (x[2 * threadIdx.x + 1] != 0) nonzero = 1;   // benign same-value race
    __syncthreads();
    if (threadIdx.x == 0) *(int*)(ws + OFF_FLAG) = (nonzero == 0) ? 1 : 0;
}

// Pack weights as float4 per (k-quad, column): Wp[z][q][j] = {W_z[j][4q+c]}.
// Values identical to source -> FMA chains stay bit-identical.
__global__ void prep_pack(const float* __restrict__ Wi2h,
                          const float* __restrict__ Wi2o,
                          const float* __restrict__ Wo2o,
                          float* __restrict__ ws) {
    const int q = blockIdx.x;            // 0..127 (k quad)
    const int z = blockIdx.y;            // 0..2
    const int j = threadIdx.x;           // 0..255 (column)
    const float* src = (z == 0) ? Wi2h : (z == 1) ? Wi2o : Wo2o;
    const float4 v = *reinterpret_cast<const float4*>(src + (size_t)j * 512 + 4 * q);
    reinterpret_cast<float4*>(ws + OFF_WP)[((size_t)z * 128 + q) * 256 + j] = v;
}

// exact-bit lane broadcast (VALU readlane; lane index wave-uniform)
__device__ __forceinline__ float rlane(float v, int l) {
    return __int_as_float(__builtin_amdgcn_readlane(__float_as_int(v), l));
}

// Bit-faithful f32 scan, register-distributed-broadcast version.
// 128 blocks x 256 threads (4 waves). Thread j owns column j of 2 batch rows.
// Input vectors (e, h, hn, o) live distributed in each wave's registers
// (lane l holds elements 4l..4l+3); per-k broadcast via v_readlane.
// Weights read once per block (no duplication): 1.5 MB/CU/step.
// FMA chains identical to R7/R8: k-ascending fmaf, e-part then h-part.
__global__ __launch_bounds__(256) void scan_all(
    const int* __restrict__ x, const float* __restrict__ emb,
    const float* __restrict__ bih, const float* __restrict__ bio,
    const float* __restrict__ boo, float* __restrict__ ws) {
    const int j = threadIdx.x;          // column 0..255
    const int lane = j & 63;
    const int row0 = blockIdx.x * 2, row1 = row0 + 1;
    const int mode64 = *(const int*)(ws + OFF_FLAG);

    const float4* __restrict__ Wh4  = reinterpret_cast<const float4*>(ws + OFF_WP);
    const float4* __restrict__ Wio4 = Wh4 + (size_t)128 * 256;
    const float4* __restrict__ Woo4 = Wh4 + (size_t)256 * 256;

    __shared__ __align__(16) float ILh[2][2][256];   // [pingpong][row][col]
    __shared__ __align__(16) float ILo[2][2][256];

    const float bih_j = bih[j], bio_j = bio[j], boo_j = boo[j];

    float4 h0v = make_float4(0.f, 0.f, 0.f, 0.f);    // h_0 = 0, distributed
    float4 h1v = make_float4(0.f, 0.f, 0.f, 0.f);
    float sum0 = 0.f, sum1 = 0.f;

    for (int t = 0; t < T_STEPS; ++t) {
        // tokens (wave-uniform scalar loads)
        const size_t xbase = (size_t)t * BSZ;
        const int tok0 = mode64 ? x[2 * (xbase + row0)] : x[xbase + row0];
        const int tok1 = mode64 ? x[2 * (xbase + row1)] : x[xbase + row1];
        // e distributed: lane l holds e[4l..4l+3]
        const float4 e0v = *reinterpret_cast<const float4*>(emb + (size_t)tok0 * HD + 4 * lane);
        const float4 e1v = *reinterpret_cast<const float4*>(emb + (size_t)tok1 * HD + 4 * lane);

        // ---- phase 1: h_new[j], o[j] = chain over k=0..511 (e part, then h part)
        float ah0 = 0.f, ah1 = 0.f, ao0 = 0.f, ao1 = 0.f;
#define P1(EC0, EC1, WHC, WOC) {                                   \
            const float s0 = rlane(EC0, q);                        \
            const float s1 = rlane(EC1, q);                        \
            ah0 = fmaf(s0, WHC, ah0); ao0 = fmaf(s0, WOC, ao0);    \
            ah1 = fmaf(s1, WHC, ah1); ao1 = fmaf(s1, WOC, ao1); }
        #pragma unroll 8
        for (int q = 0; q < 64; ++q) {              // k = 4q+m, m=0..3 (e part)
            const float4 wh = Wh4[(size_t)q * 256 + j];
            const float4 wo = Wio4[(size_t)q * 256 + j];
            P1(e0v.x, e1v.x, wh.x, wo.x)
            P1(e0v.y, e1v.y, wh.y, wo.y)
            P1(e0v.z, e1v.z, wh.z, wo.z)
            P1(e0v.w, e1v.w, wh.w, wo.w)
        }
        #pragma unroll 8
        for (int q = 0; q < 64; ++q) {              // k = 256+4q+m (h part)
            const float4 wh = Wh4[(size_t)(64 + q) * 256 + j];
            const float4 wo = Wio4[(size_t)(64 + q) * 256 + j];
            P1(h0v.x, h1v.x, wh.x, wo.x)
            P1(h0v.y, h1v.y, wh.y, wo.y)
            P1(h0v.z, h1v.z, wh.z, wo.z)
            P1(h0v.w, h1v.w, wh.w, wo.w)
        }
#undef P1
        const float hn0 = ah0 + bih_j, hn1 = ah1 + bih_j;   // + b_i2h
        const float on0 = ao0 + bio_j, on1 = ao1 + bio_j;   // + b_i2o

        // redistribute hn/o via LDS (ping-pong, one barrier per step)
        const int pp = t & 1;
        ILh[pp][0][j] = hn0; ILh[pp][1][j] = hn1;
        ILo[pp][0][j] = on0; ILo[pp][1][j] = on1;
        __syncthreads();
        h0v = *reinterpret_cast<const float4*>(&ILh[pp][0][4 * lane]);  // = hn dist
        h1v = *reinterpret_cast<const float4*>(&ILh[pp][1][4 * lane]);
        const float4 o0v = *reinterpret_cast<const float4*>(&ILo[pp][0][4 * lane]);
        const float4 o1v = *reinterpret_cast<const float4*>(&ILo[pp][1][4 * lane]);

        // ---- phase 2: out[j] = chain over k=0..511 (h_new part, then o part)
        float ac0 = 0.f, ac1 = 0.f;
#define P2(C0, C1, WC) {                                           \
            const float s0 = rlane(C0, q);                         \
            const float s1 = rlane(C1, q);                         \
            ac0 = fmaf(s0, WC, ac0);                               \
            ac1 = fmaf(s1, WC, ac1); }
        #pragma unroll 8
        for (int q = 0; q < 64; ++q) {              // h_new part
            const float4 w = Woo4[(size_t)q * 256 + j];
            P2(h0v.x, h1v.x, w.x)
            P2(h0v.y, h1v.y, w.y)
            P2(h0v.z, h1v.z, w.z)
            P2(h0v.w, h1v.w, w.w)
        }
        #pragma unroll 8
        for (int q = 0; q < 64; ++q) {              // o part
            const float4 w = Woo4[(size_t)(64 + q) * 256 + j];
            P2(o0v.x, o1v.x, w.x)
            P2(o0v.y, o1v.y, w.y)
            P2(o0v.z, o1v.z, w.z)
            P2(o0v.w, o1v.w, w.w)
        }
#undef P2
        // Sum_t accumulation, t-ascending, f32 (np.mean axis-0 order)
        sum0 += (ac0 + boo_j);
        sum1 += (ac1 + boo_j);
        // h0v/h1v now hold hn -> next step's h. No extra barrier needed:
        // next write targets buffer pp^1; this buffer is re-written only
        // after the NEXT barrier (ping-pong safe).
    }

    ws[OFF_SUM + (size_t)row0 * 256 + j] = sum0;
    ws[OFF_SUM + (size_t)row1 * 256 + j] = sum1;
}

// encoded = Sum/1024 (exact); logits = seq-k FMA + b_pred; log_softmax with
// f64-CR exp/log; first-index argmax over f32 lp.
__global__ __launch_bounds__(64) void final_k(
    const float* __restrict__ Wpred, const float* __restrict__ bpred,
    const float* __restrict__ ws, float* __restrict__ out) {
    const int b = blockIdx.x, o = threadIdx.x;
    __shared__ float enc[256];
    __shared__ float exs[64];
    __shared__ float s32s;

    #pragma unroll
    for (int u = 0; u < 4; ++u)
        enc[o * 4 + u] = ws[OFF_SUM + (size_t)b * 256 + o * 4 + u] * (1.0f / 1024.0f);
    __syncthreads();

    float acc = 0.f;
    for (int e = 0; e < 256; ++e)
        acc = fmaf(enc[e], Wpred[(size_t)o * 256 + e], acc);
    acc += bpred[o];                      // logits[b][o], f32

    float m = acc;
    #pragma unroll
    for (int d = 1; d < 64; d <<= 1) m = fmaxf(m, __shfl_xor(m, d));
    const float sh = acc - m;
    const float ex = (float)exp((double)sh);
    exs[o] = ex;
    __syncthreads();
    if (o == 0) {
        double sd = 0.0;
        for (int i = 0; i < 64; ++i) sd += (double)exs[i];
        s32s = (float)sd;
    }
    __syncthreads();
    const float log_s = (float)log((double)s32s);
    const float lp = sh - log_s;
    const float pr = (float)exp((double)lp);

    float av = lp; int ai = o;
    #pragma unroll
    for (int d = 1; d < 64; d <<= 1) {
        const float ov = __shfl_xor(av, d);
        const int oi = __shfl_xor(ai, d);
        if (ov > av || (ov == av && oi < ai)) { av = ov; ai = oi; }
    }

    out[BSZ + (size_t)b * OUTC + o] = lp;              // logprobs
    out[BSZ + 16384 + (size_t)b * OUTC + o] = pr;      // probs
    if (o == 0) out[b] = (float)ai;                    // preds
}

// ---------------- host ----------------
extern "C" void kernel_launch(void* const* d_in, const int* in_sizes, int n_in,
                              void* d_out, int out_size, void* d_ws, size_t ws_size,
                              hipStream_t stream) {
    const int*   x     = (const int*)d_in[0];
    const float* emb   = (const float*)d_in[1];
    const float* Wi2h  = (const float*)d_in[2];
    const float* b_ih  = (const float*)d_in[3];
    const float* Wi2o  = (const float*)d_in[4];
    const float* b_io  = (const float*)d_in[5];
    const float* Wo2o  = (const float*)d_in[6];
    const float* b_oo  = (const float*)d_in[7];
    const float* Wpred = (const float*)d_in[8];
    const float* b_p   = (const float*)d_in[9];
    float* ws  = (float*)d_ws;
    float* out = (float*)d_out;

    detect_x<<<1, 256, 0, stream>>>(x, ws);
    prep_pack<<<dim3(128, 3), 256, 0, stream>>>(Wi2h, Wi2o, Wo2o, ws);
    scan_all<<<dim3(128), 256, 0, stream>>>(x, emb, b_ih, b_io, b_oo, ws);
    final_k<<<dim3(256), 64, 0, stream>>>(Wpred, b_p, ws, out);
}

// Round 11
// 15767.834 us; speedup vs baseline: 2.1020x; 1.2176x over previous
//
#include <hip/hip_runtime.h>

#define T_STEPS 1024
#define BSZ 256
#define HD 256
#define OUTC 64
#define WSTEPS 16
#define NWIN (T_STEPS / WSTEPS)

// ---------------- ws layout (float offsets) ----------------
static const size_t OFF_SUM  = 0;        // [256][256] f32  (Sum_t outs)
static const size_t OFF_FLAG = 65536;    // int flag (x is int64?)
static const size_t OFF_WP   = 65792;    // 3 x [128][256] float4 packed weights

// x-dtype detector: if x is int64, all sampled high 32-bit words are zero.
__global__ void detect_x(const int* __restrict__ x, float* __restrict__ ws) {
    __shared__ int nonzero;
    if (threadIdx.x == 0) nonzero = 0;
    __syncthreads();
    if (x[2 * threadIdx.x + 1] != 0) nonzero = 1;   // benign same-value race
    __syncthreads();
    if (threadIdx.x == 0) *(int*)(ws + OFF_FLAG) = (nonzero == 0) ? 1 : 0;
}

// Pack weights as float4 per (k-quad, column): Wp[z][q][j] = {W_z[j][4q+c]}.
// Values identical to source -> FMA chains stay bit-identical.
__global__ void prep_pack(const float* __restrict__ Wi2h,
                          const float* __restrict__ Wi2o,
                          const float* __restrict__ Wo2o,
                          float* __restrict__ ws) {
    const int q = blockIdx.x;            // 0..127 (k quad)
    const int z = blockIdx.y;            // 0..2
    const int j = threadIdx.x;           // 0..255 (column)
    const float* src = (z == 0) ? Wi2h : (z == 1) ? Wi2o : Wo2o;
    const float4 v = *reinterpret_cast<const float4*>(src + (size_t)j * 512 + 4 * q);
    reinterpret_cast<float4*>(ws + OFF_WP)[((size_t)z * 128 + q) * 256 + j] = v;
}

// Bit-faithful f32 scan, 16-step-windowed version.
// 128 blocks x 256 threads; thread j owns column j of 2 batch rows.
// Per window: (A) gather e; (B) e-part chains (k=0..255) for all 16 steps in
// ONE pass over We/Weio, per-t accumulators in registers; (C) 16 sequential
// recurrence steps continuing the SAME accumulators over k=256..511 (h-part);
// (D) out-chains for all 16 steps in ONE pass over Wo2o, then t-ordered fold.
// Every per-element chain is the identical k-ascending fmaf sequence as the
// validated R7 kernel (f32 accumulator store/reload between B and C is exact).
__global__ __launch_bounds__(256) void scan_all(
    const int* __restrict__ x, const float* __restrict__ emb,
    const float* __restrict__ bih, const float* __restrict__ bio,
    const float* __restrict__ boo, float* __restrict__ ws) {
    const int j = threadIdx.x;          // column 0..255
    const int row0 = blockIdx.x * 2, row1 = row0 + 1;
    const int mode64 = *(const int*)(ws + OFF_FLAG);

    const float4* __restrict__ Wh4  = reinterpret_cast<const float4*>(ws + OFF_WP);
    const float4* __restrict__ Wio4 = Wh4 + (size_t)128 * 256;
    const float4* __restrict__ Woo4 = Wh4 + (size_t)256 * 256;

    __shared__ __align__(16) float eW[WSTEPS][2][256];    // 32 KB
    __shared__ __align__(16) float bufH[WSTEPS][2][256];  // ce_h -> hn
    __shared__ __align__(16) float bufO[WSTEPS][2][256];  // ce_o -> o
    __shared__ __align__(16) float hCur[2][256];
    __shared__ int toks[WSTEPS][2];

    const float bih_j = bih[j], bio_j = bio[j], boo_j = boo[j];

    hCur[0][j] = 0.f; hCur[1][j] = 0.f;   // h_0 = 0
    float sum0 = 0.f, sum1 = 0.f;
    __syncthreads();

    for (int w = 0; w < NWIN; ++w) {
        // ---- A: tokens + e for the window
        if (j < 2 * WSTEPS) {
            const int t = j & (WSTEPS - 1), r = j >> 4;
            const int idx = (w * WSTEPS + t) * BSZ + row0 + r;
            toks[t][r] = mode64 ? x[2 * idx] : x[idx];
        }
        __syncthreads();
        #pragma unroll
        for (int t = 0; t < WSTEPS; ++t) {
            eW[t][0][j] = emb[(size_t)toks[t][0] * HD + j];
            eW[t][1][j] = emb[(size_t)toks[t][1] * HD + j];
        }
        __syncthreads();

        // ---- B: e-part chains (k = 0..255), one weight pass for 16 steps
        float aH[WSTEPS][2], aO[WSTEPS][2];
        #pragma unroll
        for (int t = 0; t < WSTEPS; ++t) {
            aH[t][0] = 0.f; aH[t][1] = 0.f; aO[t][0] = 0.f; aO[t][1] = 0.f;
        }
        #pragma unroll 2
        for (int q = 0; q < 64; ++q) {
            const float4 wh = Wh4[(size_t)q * 256 + j];
            const float4 wo = Wio4[(size_t)q * 256 + j];
            #pragma unroll
            for (int t = 0; t < WSTEPS; ++t) {
                #pragma unroll
                for (int r = 0; r < 2; ++r) {
                    const float4 e = reinterpret_cast<const float4*>(eW[t][r])[q];
                    float h = aH[t][r], o = aO[t][r];
                    h = fmaf(e.x, wh.x, h); o = fmaf(e.x, wo.x, o);
                    h = fmaf(e.y, wh.y, h); o = fmaf(e.y, wo.y, o);
                    h = fmaf(e.z, wh.z, h); o = fmaf(e.z, wo.z, o);
                    h = fmaf(e.w, wh.w, h); o = fmaf(e.w, wo.w, o);
                    aH[t][r] = h; aO[t][r] = o;
                }
            }
        }
        #pragma unroll
        for (int t = 0; t < WSTEPS; ++t) {
            bufH[t][0][j] = aH[t][0]; bufH[t][1][j] = aH[t][1];
            bufO[t][0][j] = aO[t][0]; bufO[t][1][j] = aO[t][1];
        }
        __syncthreads();

        // ---- C: 16 sequential recurrence steps (h-part, k = 256..511)
        for (int t = 0; t < WSTEPS; ++t) {
            float ah0 = bufH[t][0][j], ah1 = bufH[t][1][j];
            float ao0 = bufO[t][0][j], ao1 = bufO[t][1][j];
            #pragma unroll 4
            for (int q = 0; q < 64; ++q) {
                const float4 wh = Wh4[(size_t)(64 + q) * 256 + j];
                const float4 wo = Wio4[(size_t)(64 + q) * 256 + j];
                const float4 h0 = reinterpret_cast<const float4*>(hCur[0])[q];
                const float4 h1 = reinterpret_cast<const float4*>(hCur[1])[q];
                ah0 = fmaf(h0.x, wh.x, ah0); ao0 = fmaf(h0.x, wo.x, ao0);
                ah1 = fmaf(h1.x, wh.x, ah1); ao1 = fmaf(h1.x, wo.x, ao1);
                ah0 = fmaf(h0.y, wh.y, ah0); ao0 = fmaf(h0.y, wo.y, ao0);
                ah1 = fmaf(h1.y, wh.y, ah1); ao1 = fmaf(h1.y, wo.y, ao1);
                ah0 = fmaf(h0.z, wh.z, ah0); ao0 = fmaf(h0.z, wo.z, ao0);
                ah1 = fmaf(h1.z, wh.z, ah1); ao1 = fmaf(h1.z, wo.z, ao1);
                ah0 = fmaf(h0.w, wh.w, ah0); ao0 = fmaf(h0.w, wo.w, ao0);
                ah1 = fmaf(h1.w, wh.w, ah1); ao1 = fmaf(h1.w, wo.w, ao1);
            }
            const float hn0 = ah0 + bih_j, hn1 = ah1 + bih_j;   // + b_i2h
            const float on0 = ao0 + bio_j, on1 = ao1 + bio_j;   // + b_i2o
            __syncthreads();                 // all hCur reads done
            hCur[0][j] = hn0; hCur[1][j] = hn1;
            bufH[t][0][j] = hn0; bufH[t][1][j] = hn1;   // keep for phase D
            bufO[t][0][j] = on0; bufO[t][1][j] = on1;
            __syncthreads();                 // hCur/buffers published
        }

        // ---- D: out-chains for 16 steps, one pass over Wo2o (k-chunked,
        // per-t accumulators continue each chain in k order)
        float a2[WSTEPS][2];
        #pragma unroll
        for (int t = 0; t < WSTEPS; ++t) { a2[t][0] = 0.f; a2[t][1] = 0.f; }
        #pragma unroll 2
        for (int q = 0; q < 64; ++q) {       // hn part (k = 0..255)
            const float4 w4 = Woo4[(size_t)q * 256 + j];
            #pragma unroll
            for (int t = 0; t < WSTEPS; ++t) {
                #pragma unroll
                for (int r = 0; r < 2; ++r) {
                    const float4 v = reinterpret_cast<const float4*>(bufH[t][r])[q];
                    float a = a2[t][r];
                    a = fmaf(v.x, w4.x, a); a = fmaf(v.y, w4.y, a);
                    a = fmaf(v.z, w4.z, a); a = fmaf(v.w, w4.w, a);
                    a2[t][r] = a;
                }
            }
        }
        #pragma unroll 2
        for (int q = 0; q < 64; ++q) {       // o part (k = 256..511)
            const float4 w4 = Woo4[(size_t)(64 + q) * 256 + j];
            #pragma unroll
            for (int t = 0; t < WSTEPS; ++t) {
                #pragma unroll
                for (int r = 0; r < 2; ++r) {
                    const float4 v = reinterpret_cast<const float4*>(bufO[t][r])[q];
                    float a = a2[t][r];
                    a = fmaf(v.x, w4.x, a); a = fmaf(v.y, w4.y, a);
                    a = fmaf(v.z, w4.z, a); a = fmaf(v.w, w4.w, a);
                    a2[t][r] = a;
                }
            }
        }
        // t-ordered fold (np.mean axis-0 order), + b_oo per element
        #pragma unroll
        for (int t = 0; t < WSTEPS; ++t) {
            sum0 += (a2[t][0] + boo_j);
            sum1 += (a2[t][1] + boo_j);
        }
        __syncthreads();                     // protect buffers for next window
    }

    ws[OFF_SUM + (size_t)row0 * 256 + j] = sum0;
    ws[OFF_SUM + (size_t)row1 * 256 + j] = sum1;
}

// encoded = Sum/1024 (exact); logits = seq-k FMA + b_pred; log_softmax with
// f64-CR exp/log; first-index argmax over f32 lp.
__global__ __launch_bounds__(64) void final_k(
    const float* __restrict__ Wpred, const float* __restrict__ bpred,
    const float* __restrict__ ws, float* __restrict__ out) {
    const int b = blockIdx.x, o = threadIdx.x;
    __shared__ float enc[256];
    __shared__ float exs[64];
    __shared__ float s32s;

    #pragma unroll
    for (int u = 0; u < 4; ++u)
        enc[o * 4 + u] = ws[OFF_SUM + (size_t)b * 256 + o * 4 + u] * (1.0f / 1024.0f);
    __syncthreads();

    float acc = 0.f;
    for (int e = 0; e < 256; ++e)
        acc = fmaf(enc[e], Wpred[(size_t)o * 256 + e], acc);
    acc += bpred[o];                      // logits[b][o], f32

    float m = acc;
    #pragma unroll
    for (int d = 1; d < 64; d <<= 1) m = fmaxf(m, __shfl_xor(m, d));
    const float sh = acc - m;
    const float ex = (float)exp((double)sh);
    exs[o] = ex;
    __syncthreads();
    if (o == 0) {
        double sd = 0.0;
        for (int i = 0; i < 64; ++i) sd += (double)exs[i];
        s32s = (float)sd;
    }
    __syncthreads();
    const float log_s = (float)log((double)s32s);
    const float lp = sh - log_s;
    const float pr = (float)exp((double)lp);

    float av = lp; int ai = o;
    #pragma unroll
    for (int d = 1; d < 64; d <<= 1) {
        const float ov = __shfl_xor(av, d);
        const int oi = __shfl_xor(ai, d);
        if (ov > av || (ov == av && oi < ai)) { av = ov; ai = oi; }
    }

    out[BSZ + (size_t)b * OUTC + o] = lp;              // logprobs
    out[BSZ + 16384 + (size_t)b * OUTC + o] = pr;      // probs
    if (o == 0) out[b] = (float)ai;                    // preds
}

// ---------------- host ----------------
extern "C" void kernel_launch(void* const* d_in, const int* in_sizes, int n_in,
                              void* d_out, int out_size, void* d_ws, size_t ws_size,
                              hipStream_t stream) {
    const int*   x     = (const int*)d_in[0];
    const float* emb   = (const float*)d_in[1];
    const float* Wi2h  = (const float*)d_in[2];
    const float* b_ih  = (const float*)d_in[3];
    const float* Wi2o  = (const float*)d_in[4];
    const float* b_io  = (const float*)d_in[5];
    const float* Wo2o  = (const float*)d_in[6];
    const float* b_oo  = (const float*)d_in[7];
    const float* Wpred = (const float*)d_in[8];
    const float* b_p   = (const float*)d_in[9];
    float* ws  = (float*)d_ws;
    float* out = (float*)d_out;

    detect_x<<<1, 256, 0, stream>>>(x, ws);
    prep_pack<<<dim3(128, 3), 256, 0, stream>>>(Wi2h, Wi2o, Wo2o, ws);
    scan_all<<<dim3(128), 256, 0, stream>>>(x, emb, b_ih, b_io, b_oo, ws);
    final_k<<<dim3(256), 64, 0, stream>>>(Wpred, b_p, ws, out);
}

// Round 12
// 10455.341 us; speedup vs baseline: 3.1701x; 1.5081x over previous
//
#include <hip/hip_runtime.h>

#define T_STEPS 1024
#define BSZ 256
#define HD 256
#define OUTC 64
#define WSTEPS 16
#define NWIN (T_STEPS / WSTEPS)

// ---------------- ws layout (float offsets) ----------------
static const size_t OFF_SUM  = 0;        // [256][256] f32  (Sum_t outs)
static const size_t OFF_FLAG = 65536;    // int flag (x is int64?)
static const size_t OFF_WP   = 65792;    // 3 x [128][256] float4 packed weights

// x-dtype detector: if x is int64, all sampled high 32-bit words are zero.
__global__ void detect_x(const int* __restrict__ x, float* __restrict__ ws) {
    __shared__ int nonzero;
    if (threadIdx.x == 0) nonzero = 0;
    __syncthreads();
    if (x[2 * threadIdx.x + 1] != 0) nonzero = 1;   // benign same-value race
    __syncthreads();
    if (threadIdx.x == 0) *(int*)(ws + OFF_FLAG) = (nonzero == 0) ? 1 : 0;
}

// Pack weights as float4 per (k-quad, column): Wp[z][q][j] = {W_z[j][4q+c]}.
// Values identical to source -> FMA chains stay bit-identical.
__global__ void prep_pack(const float* __restrict__ Wi2h,
                          const float* __restrict__ Wi2o,
                          const float* __restrict__ Wo2o,
                          float* __restrict__ ws) {
    const int q = blockIdx.x;            // 0..127 (k quad)
    const int z = blockIdx.y;            // 0..2
    const int j = threadIdx.x;           // 0..255 (column)
    const float* src = (z == 0) ? Wi2h : (z == 1) ? Wi2o : Wo2o;
    const float4 v = *reinterpret_cast<const float4*>(src + (size_t)j * 512 + 4 * q);
    reinterpret_cast<float4*>(ws + OFF_WP)[((size_t)z * 128 + q) * 256 + j] = v;
}

// Bit-faithful f32 scan; 256 blocks x 256 threads, 1 batch row per block.
// Thread j owns column j. Per 16-step window:
//   A : gather tokens + e rows; publish carried h as hIn[0].
//   B : e-part chains (k=0..255) for hn and o, one pass over We/Weio,
//       per-t partials in registers.
//   C : 16 sequential recurrence steps. h-part weights (Wi2h k=256..511)
//       live in REGISTERS (whr[64], preloaded once) -> zero weight traffic;
//       h broadcast via LDS. Writes hIn[t+1].
//   D2: o's h-part (Whio k=256..511) batched for all 16 steps in one
//       256 KB pass, continuing the same k-ascending chains; o -> bufO.
//   D : out-chains (Wo2o) for 16 steps in one pass; t-ordered fold into sum.
// Every output element's fmaf chain is the identical k-ascending sequence of
// the validated R7 kernel (register-carried f32 partials are exact).
__global__ __launch_bounds__(256, 1) void scan_all(
    const int* __restrict__ x, const float* __restrict__ emb,
    const float* __restrict__ bih, const float* __restrict__ bio,
    const float* __restrict__ boo, float* __restrict__ ws) {
    const int j = threadIdx.x;          // column 0..255
    const int row = blockIdx.x;         // batch row
    const int mode64 = *(const int*)(ws + OFF_FLAG);

    const float4* __restrict__ Wh4  = reinterpret_cast<const float4*>(ws + OFF_WP);
    const float4* __restrict__ Wio4 = Wh4 + (size_t)128 * 256;
    const float4* __restrict__ Woo4 = Wh4 + (size_t)256 * 256;

    // h-part of Wi2h for column j, resident in registers (256 VGPRs)
    float4 whr[64];
    #pragma unroll
    for (int q = 0; q < 64; ++q) whr[q] = Wh4[(size_t)(64 + q) * 256 + j];

    __shared__ __align__(16) float eW[WSTEPS][256];       // 16 KB
    __shared__ __align__(16) float hIn[WSTEPS + 1][256];  // 17 KB
    __shared__ __align__(16) float bufO[WSTEPS][256];     // 16 KB
    __shared__ int toks[WSTEPS];

    const float bih_j = bih[j], bio_j = bio[j], boo_j = boo[j];

    float hCarry = 0.f;                  // h_0 = 0
    float sum = 0.f;

    for (int w = 0; w < NWIN; ++w) {
        // ---- A: tokens + e for the window; publish carried h
        if (j < WSTEPS) {
            const int idx = (w * WSTEPS + j) * BSZ + row;
            toks[j] = mode64 ? x[2 * idx] : x[idx];
        }
        hIn[0][j] = hCarry;
        __syncthreads();
        #pragma unroll
        for (int t = 0; t < WSTEPS; ++t)
            eW[t][j] = emb[(size_t)toks[t] * HD + j];
        __syncthreads();

        // ---- B: e-part chains (k = 0..255), one weight pass for 16 steps
        float aH[WSTEPS], aO[WSTEPS];
        #pragma unroll
        for (int t = 0; t < WSTEPS; ++t) { aH[t] = 0.f; aO[t] = 0.f; }
        #pragma unroll 2
        for (int q = 0; q < 64; ++q) {
            const float4 wh = Wh4[(size_t)q * 256 + j];
            const float4 wo = Wio4[(size_t)q * 256 + j];
            #pragma unroll
            for (int t = 0; t < WSTEPS; ++t) {
                const float4 e = reinterpret_cast<const float4*>(eW[t])[q];
                float h = aH[t], o = aO[t];
                h = fmaf(e.x, wh.x, h); o = fmaf(e.x, wo.x, o);
                h = fmaf(e.y, wh.y, h); o = fmaf(e.y, wo.y, o);
                h = fmaf(e.z, wh.z, h); o = fmaf(e.z, wo.z, o);
                h = fmaf(e.w, wh.w, h); o = fmaf(e.w, wo.w, o);
                aH[t] = h; aO[t] = o;
            }
        }

        // ---- C: 16 sequential recurrence steps, register weights, no VMEM
        #pragma unroll 1
        for (int t = 0; t < WSTEPS; ++t) {
            float ah = aH[t];
            #pragma unroll
            for (int q = 0; q < 64; ++q) {
                const float4 h4 = reinterpret_cast<const float4*>(hIn[t])[q];
                ah = fmaf(h4.x, whr[q].x, ah);
                ah = fmaf(h4.y, whr[q].y, ah);
                ah = fmaf(h4.z, whr[q].z, ah);
                ah = fmaf(h4.w, whr[q].w, ah);
            }
            const float hn = ah + bih_j;           // + b_i2h
            hIn[t + 1][j] = hn;                    // slot t+1 != read slot t
            hCarry = hn;                           // survives to next window
            __syncthreads();
        }

        // ---- D2: o's h-part (k = 256..511) batched over the window
        #pragma unroll 2
        for (int q = 0; q < 64; ++q) {
            const float4 w4 = Wio4[(size_t)(64 + q) * 256 + j];
            #pragma unroll
            for (int t = 0; t < WSTEPS; ++t) {
                const float4 h4 = reinterpret_cast<const float4*>(hIn[t])[q];
                float o = aO[t];
                o = fmaf(h4.x, w4.x, o); o = fmaf(h4.y, w4.y, o);
                o = fmaf(h4.z, w4.z, o); o = fmaf(h4.w, w4.w, o);
                aO[t] = o;
            }
        }
        #pragma unroll
        for (int t = 0; t < WSTEPS; ++t) bufO[t][j] = aO[t] + bio_j;  // + b_i2o
        __syncthreads();

        // ---- D: out-chains, one pass over Wo2o (hn part then o part)
        float a2[WSTEPS];
        #pragma unroll
        for (int t = 0; t < WSTEPS; ++t) a2[t] = 0.f;
        #pragma unroll 2
        for (int q = 0; q < 64; ++q) {       // hn part (k = 0..255)
            const float4 w4 = Woo4[(size_t)q * 256 + j];
            #pragma unroll
            for (int t = 0; t < WSTEPS; ++t) {
                const float4 v = reinterpret_cast<const float4*>(hIn[t + 1])[q];
                float a = a2[t];
                a = fmaf(v.x, w4.x, a); a = fmaf(v.y, w4.y, a);
                a = fmaf(v.z, w4.z, a); a = fmaf(v.w, w4.w, a);
                a2[t] = a;
            }
        }
        #pragma unroll 2
        for (int q = 0; q < 64; ++q) {       // o part (k = 256..511)
            const float4 w4 = Woo4[(size_t)(64 + q) * 256 + j];
            #pragma unroll
            for (int t = 0; t < WSTEPS; ++t) {
                const float4 v = reinterpret_cast<const float4*>(bufO[t])[q];
                float a = a2[t];
                a = fmaf(v.x, w4.x, a); a = fmaf(v.y, w4.y, a);
                a = fmaf(v.z, w4.z, a); a = fmaf(v.w, w4.w, a);
                a2[t] = a;
            }
        }
        // t-ordered fold (np.mean axis-0 order), + b_oo per element
        #pragma unroll
        for (int t = 0; t < WSTEPS; ++t) sum += (a2[t] + boo_j);
        // no end barrier needed: next A writes toks/hIn[0]/eW, all disjoint
        // from D's reads (hIn[1..16], bufO); eW writes are after A's barrier.
    }

    ws[OFF_SUM + (size_t)row * 256 + j] = sum;
}

// encoded = Sum/1024 (exact); logits = seq-k FMA + b_pred; log_softmax with
// f64-CR exp/log; first-index argmax over f32 lp.
__global__ __launch_bounds__(64) void final_k(
    const float* __restrict__ Wpred, const float* __restrict__ bpred,
    const float* __restrict__ ws, float* __restrict__ out) {
    const int b = blockIdx.x, o = threadIdx.x;
    __shared__ float enc[256];
    __shared__ float exs[64];
    __shared__ float s32s;

    #pragma unroll
    for (int u = 0; u < 4; ++u)
        enc[o * 4 + u] = ws[OFF_SUM + (size_t)b * 256 + o * 4 + u] * (1.0f / 1024.0f);
    __syncthreads();

    float acc = 0.f;
    for (int e = 0; e < 256; ++e)
        acc = fmaf(enc[e], Wpred[(size_t)o * 256 + e], acc);
    acc += bpred[o];                      // logits[b][o], f32

    float m = acc;
    #pragma unroll
    for (int d = 1; d < 64; d <<= 1) m = fmaxf(m, __shfl_xor(m, d));
    const float sh = acc - m;
    const float ex = (float)exp((double)sh);
    exs[o] = ex;
    __syncthreads();
    if (o == 0) {
        double sd = 0.0;
        for (int i = 0; i < 64; ++i) sd += (double)exs[i];
        s32s = (float)sd;
    }
    __syncthreads();
    const float log_s = (float)log((double)s32s);
    const float lp = sh - log_s;
    const float pr = (float)exp((double)lp);

    float av = lp; int ai = o;
    #pragma unroll
    for (int d = 1; d < 64; d <<= 1) {
        const float ov = __shfl_xor(av, d);
        const int oi = __shfl_xor(ai, d);
        if (ov > av || (ov == av && oi < ai)) { av = ov; ai = oi; }
    }

    out[BSZ + (size_t)b * OUTC + o] = lp;              // logprobs
    out[BSZ + 16384 + (size_t)b * OUTC + o] = pr;      // probs
    if (o == 0) out[b] = (float)ai;                    // preds
}

// ---------------- host ----------------
extern "C" void kernel_launch(void* const* d_in, const int* in_sizes, int n_in,
                              void* d_out, int out_size, void* d_ws, size_t ws_size,
                              hipStream_t stream) {
    const int*   x     = (const int*)d_in[0];
    const float* emb   = (const float*)d_in[1];
    const float* Wi2h  = (const float*)d_in[2];
    const float* b_ih  = (const float*)d_in[3];
    const float* Wi2o  = (const float*)d_in[4];
    const float* b_io  = (const float*)d_in[5];
    const float* Wo2o  = (const float*)d_in[6];
    const float* b_oo  = (const float*)d_in[7];
    const float* Wpred = (const float*)d_in[8];
    const float* b_p   = (const float*)d_in[9];
    float* ws  = (float*)d_ws;
    float* out = (float*)d_out;

    detect_x<<<1, 256, 0, stream>>>(x, ws);
    prep_pack<<<dim3(128, 3), 256, 0, stream>>>(Wi2h, Wi2o, Wo2o, ws);
    scan_all<<<dim3(256), 256, 0, stream>>>(x, emb, b_ih, b_io, b_oo, ws);
    final_k<<<dim3(256), 64, 0, stream>>>(Wpred, b_p, ws, out);
}

// Round 13
// 9221.255 us; speedup vs baseline: 3.5943x; 1.1338x over previous
//
#include <hip/hip_runtime.h>

#define T_STEPS 1024
#define BSZ 256
#define HD 256
#define OUTC 64
#define WSTEPS 16
#define NWIN (T_STEPS / WSTEPS)

// ---------------- ws layout (float offsets) ----------------
static const size_t OFF_SUM  = 0;        // [256][256] f32  (Sum_t outs)
static const size_t OFF_FLAG = 65536;    // int flag (x is int64?)
static const size_t OFF_WP   = 65792;    // 3 x [128][256] float4 packed weights

// x-dtype detector: if x is int64, all sampled high 32-bit words are zero.
__global__ void detect_x(const int* __restrict__ x, float* __restrict__ ws) {
    __shared__ int nonzero;
    if (threadIdx.x == 0) nonzero = 0;
    __syncthreads();
    if (x[2 * threadIdx.x + 1] != 0) nonzero = 1;   // benign same-value race
    __syncthreads();
    if (threadIdx.x == 0) *(int*)(ws + OFF_FLAG) = (nonzero == 0) ? 1 : 0;
}

// Pack weights as float4 per (k-quad, column): Wp[z][q][j] = {W_z[j][4q+c]}.
// Values identical to source -> FMA chains stay bit-identical.
__global__ void prep_pack(const float* __restrict__ Wi2h,
                          const float* __restrict__ Wi2o,
                          const float* __restrict__ Wo2o,
                          float* __restrict__ ws) {
    const int q = blockIdx.x;            // 0..127 (k quad)
    const int z = blockIdx.y;            // 0..2
    const int j = threadIdx.x;           // 0..255 (column)
    const float* src = (z == 0) ? Wi2h : (z == 1) ? Wi2o : Wo2o;
    const float4 v = *reinterpret_cast<const float4*>(src + (size_t)j * 512 + 4 * q);
    reinterpret_cast<float4*>(ws + OFF_WP)[((size_t)z * 128 + q) * 256 + j] = v;
}

// exact-bit wave broadcast: value of v at lane l (SGPR-indexed readlane)
__device__ __forceinline__ float RLf(float v, int l) {
    return __int_as_float(__builtin_amdgcn_readlane(__float_as_int(v), l));
}

// Bit-faithful f32 scan, readlane-broadcast version.
// 256 blocks x 256 threads, 1 batch row per block; thread j owns column j.
// Shared operand vectors (e_t, h_t, o_t) live DISTRIBUTED in wave registers
// (lane l holds elements 4l..4l+3, one b128 load each); per-k broadcasts are
// v_readlane (VALU) instead of LDS reads -> DS pipe traffic collapses.
// Phases per 16-step window (chains = identical k-ascending fmaf order):
//   A : tokens; publish carried h into hHist[0]; load e4[t] from global.
//   B : e-part chains (k=0..255) for hn and o, one pass over We/Weio.
//   C : 16 sequential recurrence steps; h-part weights in registers (whr);
//       h broadcast via readlane from one b128-loaded quad; t-loop rolled
//       (aH partials hop through LDS, exact f32 store/reload).
//   D2: o's h-part (k=256..511) batched, 2 groups of 8 t.
//   D : out-chains (hn part then o part), 2 groups of 8 t; t-ordered fold.
__global__ __launch_bounds__(256, 1) void scan_all(
    const int* __restrict__ x, const float* __restrict__ emb,
    const float* __restrict__ bih, const float* __restrict__ bio,
    const float* __restrict__ boo, float* __restrict__ ws) {
    const int j = threadIdx.x;          // column 0..255
    const int lane = j & 63;
    const int row = blockIdx.x;         // batch row
    const int mode64 = *(const int*)(ws + OFF_FLAG);

    const float4* __restrict__ Wh4  = reinterpret_cast<const float4*>(ws + OFF_WP);
    const float4* __restrict__ Wio4 = Wh4 + (size_t)128 * 256;
    const float4* __restrict__ Woo4 = Wh4 + (size_t)256 * 256;

    // h-part of Wi2h for column j, resident in registers (256 VGPRs)
    float4 whr[64];
    #pragma unroll
    for (int q = 0; q < 64; ++q) whr[q] = Wh4[(size_t)(64 + q) * 256 + j];

    __shared__ __align__(16) float hHist[WSTEPS + 1][256];  // h states
    __shared__ __align__(16) float oHist[WSTEPS][256];      // o values
    __shared__ float aHb[WSTEPS][256];                      // aH partial hop
    __shared__ int toks[WSTEPS];

    const float bih_j = bih[j], bio_j = bio[j], boo_j = boo[j];

    float carry = 0.f;                  // h_0 = 0 (own column value)
    float sum = 0.f;

    for (int w = 0; w < NWIN; ++w) {
        // ---- A: tokens + carried h
        if (j < WSTEPS) {
            const int idx = (w * WSTEPS + j) * BSZ + row;
            toks[j] = mode64 ? x[2 * idx] : x[idx];
        }
        hHist[0][j] = carry;
        __syncthreads();

        // e distributed in registers: lane l holds e[4l..4l+3]
        float4 e4[WSTEPS];
        #pragma unroll
        for (int t = 0; t < WSTEPS; ++t)
            e4[t] = *reinterpret_cast<const float4*>(emb + (size_t)toks[t] * HD + 4 * lane);

        // ---- B: e-part chains (k = 0..255), one weight pass, readlane bcast
        float aH[WSTEPS], aO[WSTEPS];
        #pragma unroll
        for (int t = 0; t < WSTEPS; ++t) { aH[t] = 0.f; aO[t] = 0.f; }
        #pragma unroll 2
        for (int q = 0; q < 64; ++q) {
            const float4 wh = Wh4[(size_t)q * 256 + j];
            const float4 wo = Wio4[(size_t)q * 256 + j];
            #pragma unroll
            for (int t = 0; t < WSTEPS; ++t) {
                float s;
                s = RLf(e4[t].x, q); aH[t] = fmaf(s, wh.x, aH[t]); aO[t] = fmaf(s, wo.x, aO[t]);
                s = RLf(e4[t].y, q); aH[t] = fmaf(s, wh.y, aH[t]); aO[t] = fmaf(s, wo.y, aO[t]);
                s = RLf(e4[t].z, q); aH[t] = fmaf(s, wh.z, aH[t]); aO[t] = fmaf(s, wo.z, aO[t]);
                s = RLf(e4[t].w, q); aH[t] = fmaf(s, wh.w, aH[t]); aO[t] = fmaf(s, wo.w, aO[t]);
            }
        }
        #pragma unroll
        for (int t = 0; t < WSTEPS; ++t) aHb[t][j] = aH[t];   // own slot, exact

        // ---- C: 16 sequential steps; whr in regs, h via readlane
        for (int t = 0; t < WSTEPS; ++t) {
            __syncthreads();             // hHist[t] complete (prev write)
            const float4 h4 = *reinterpret_cast<const float4*>(&hHist[t][4 * lane]);
            float ah = aHb[t][j];
            #pragma unroll
            for (int q = 0; q < 64; ++q) {
                ah = fmaf(RLf(h4.x, q), whr[q].x, ah);
                ah = fmaf(RLf(h4.y, q), whr[q].y, ah);
                ah = fmaf(RLf(h4.z, q), whr[q].z, ah);
                ah = fmaf(RLf(h4.w, q), whr[q].w, ah);
            }
            hHist[t + 1][j] = ah + bih_j;          // + b_i2h
        }
        __syncthreads();                 // all h states published
        carry = hHist[WSTEPS][j];        // own value

        // ---- D2: o's h-part (k = 256..511), 2 groups of 8 t
        #pragma unroll
        for (int g = 0; g < 2; ++g) {
            float4 hv[8];
            #pragma unroll
            for (int u = 0; u < 8; ++u)
                hv[u] = *reinterpret_cast<const float4*>(&hHist[g * 8 + u][4 * lane]);
            #pragma unroll 2
            for (int q = 0; q < 64; ++q) {
                const float4 w4 = Wio4[(size_t)(64 + q) * 256 + j];
                #pragma unroll
                for (int u = 0; u < 8; ++u) {
                    const int t = g * 8 + u;
                    float s;
                    s = RLf(hv[u].x, q); aO[t] = fmaf(s, w4.x, aO[t]);
                    s = RLf(hv[u].y, q); aO[t] = fmaf(s, w4.y, aO[t]);
                    s = RLf(hv[u].z, q); aO[t] = fmaf(s, w4.z, aO[t]);
                    s = RLf(hv[u].w, q); aO[t] = fmaf(s, w4.w, aO[t]);
                }
            }
        }
        #pragma unroll
        for (int t = 0; t < WSTEPS; ++t) oHist[t][j] = aO[t] + bio_j;  // + b_i2o
        __syncthreads();                 // o published

        // ---- D: out-chains (hn part k=0..255, then o part k=256..511)
        float a2[WSTEPS];
        #pragma unroll
        for (int t = 0; t < WSTEPS; ++t) a2[t] = 0.f;
        #pragma unroll
        for (int g = 0; g < 2; ++g) {
            float4 hv[8];
            #pragma unroll
            for (int u = 0; u < 8; ++u)
                hv[u] = *reinterpret_cast<const float4*>(&hHist[g * 8 + u + 1][4 * lane]);
            #pragma unroll 2
            for (int q = 0; q < 64; ++q) {
                const float4 w4 = Woo4[(size_t)q * 256 + j];
                #pragma unroll
                for (int u = 0; u < 8; ++u) {
                    const int t = g * 8 + u;
                    float s;
                    s = RLf(hv[u].x, q); a2[t] = fmaf(s, w4.x, a2[t]);
                    s = RLf(hv[u].y, q); a2[t] = fmaf(s, w4.y, a2[t]);
                    s = RLf(hv[u].z, q); a2[t] = fmaf(s, w4.z, a2[t]);
                    s = RLf(hv[u].w, q); a2[t] = fmaf(s, w4.w, a2[t]);
                }
            }
            float4 ov[8];
            #pragma unroll
            for (int u = 0; u < 8; ++u)
                ov[u] = *reinterpret_cast<const float4*>(&oHist[g * 8 + u][4 * lane]);
            #pragma unroll 2
            for (int q = 0; q < 64; ++q) {
                const float4 w4 = Woo4[(size_t)(64 + q) * 256 + j];
                #pragma unroll
                for (int u = 0; u < 8; ++u) {
                    const int t = g * 8 + u;
                    float s;
                    s = RLf(ov[u].x, q); a2[t] = fmaf(s, w4.x, a2[t]);
                    s = RLf(ov[u].y, q); a2[t] = fmaf(s, w4.y, a2[t]);
                    s = RLf(ov[u].z, q); a2[t] = fmaf(s, w4.z, a2[t]);
                    s = RLf(ov[u].w, q); a2[t] = fmaf(s, w4.w, a2[t]);
                }
            }
        }
        // t-ordered fold (np.mean axis-0 order), + b_oo per element
        #pragma unroll
        for (int t = 0; t < WSTEPS; ++t) sum += (a2[t] + boo_j);
        // no end barrier needed: next writes (toks, hHist[0]) are not read by
        // any straggler (D reads hHist[1..16]/oHist only), and next window's
        // hHist[1..] writes are gated by C's top-of-loop barrier.
    }

    ws[OFF_SUM + (size_t)row * 256 + j] = sum;
}

// encoded = Sum/1024 (exact); logits = seq-k FMA + b_pred; log_softmax with
// f64-CR exp/log; first-index argmax over f32 lp.
__global__ __launch_bounds__(64) void final_k(
    const float* __restrict__ Wpred, const float* __restrict__ bpred,
    const float* __restrict__ ws, float* __restrict__ out) {
    const int b = blockIdx.x, o = threadIdx.x;
    __shared__ float enc[256];
    __shared__ float exs[64];
    __shared__ float s32s;

    #pragma unroll
    for (int u = 0; u < 4; ++u)
        enc[o * 4 + u] = ws[OFF_SUM + (size_t)b * 256 + o * 4 + u] * (1.0f / 1024.0f);
    __syncthreads();

    float acc = 0.f;
    for (int e = 0; e < 256; ++e)
        acc = fmaf(enc[e], Wpred[(size_t)o * 256 + e], acc);
    acc += bpred[o];                      // logits[b][o], f32

    float m = acc;
    #pragma unroll
    for (int d = 1; d < 64; d <<= 1) m = fmaxf(m, __shfl_xor(m, d));
    const float sh = acc - m;
    const float ex = (float)exp((double)sh);
    exs[o] = ex;
    __syncthreads();
    if (o == 0) {
        double sd = 0.0;
        for (int i = 0; i < 64; ++i) sd += (double)exs[i];
        s32s = (float)sd;
    }
    __syncthreads();
    const float log_s = (float)log((double)s32s);
    const float lp = sh - log_s;
    const float pr = (float)exp((double)lp);

    float av = lp; int ai = o;
    #pragma unroll
    for (int d = 1; d < 64; d <<= 1) {
        const float ov = __shfl_xor(av, d);
        const int oi = __shfl_xor(ai, d);
        if (ov > av || (ov == av && oi < ai)) { av = ov; ai = oi; }
    }

    out[BSZ + (size_t)b * OUTC + o] = lp;              // logprobs
    out[BSZ + 16384 + (size_t)b * OUTC + o] = pr;      // probs
    if (o == 0) out[b] = (float)ai;                    // preds
}

// ---------------- host ----------------
extern "C" void kernel_launch(void* const* d_in, const int* in_sizes, int n_in,
                              void* d_out, int out_size, void* d_ws, size_t ws_size,
                              hipStream_t stream) {
    const int*   x     = (const int*)d_in[0];
    const float* emb   = (const float*)d_in[1];
    const float* Wi2h  = (const float*)d_in[2];
    const float* b_ih  = (const float*)d_in[3];
    const float* Wi2o  = (const float*)d_in[4];
    const float* b_io  = (const float*)d_in[5];
    const float* Wo2o  = (const float*)d_in[6];
    const float* b_oo  = (const float*)d_in[7];
    const float* Wpred = (const float*)d_in[8];
    const float* b_p   = (const float*)d_in[9];
    float* ws  = (float*)d_ws;
    float* out = (float*)d_out;

    detect_x<<<1, 256, 0, stream>>>(x, ws);
    prep_pack<<<dim3(128, 3), 256, 0, stream>>>(Wi2h, Wi2o, Wo2o, ws);
    scan_all<<<dim3(256), 256, 0, stream>>>(x, emb, b_ih, b_io, b_oo, ws);
    final_k<<<dim3(256), 64, 0, stream>>>(Wpred, b_p, ws, out);
}

// Round 14
// 8824.174 us; speedup vs baseline: 3.7561x; 1.0450x over previous
//
#include <hip/hip_runtime.h>

#define T_STEPS 1024
#define BSZ 256
#define HD 256
#define OUTC 64
#define WSTEPS 16
#define NWIN (T_STEPS / WSTEPS)
#define WREG 56   // k-quads of Wi2h h-part held in registers
#define WTAIL 8   // k-quads of Wi2h h-part held in LDS

// ---------------- ws layout (float offsets) ----------------
static const size_t OFF_SUM  = 0;        // [256][256] f32  (Sum_t outs)
static const size_t OFF_FLAG = 65536;    // int flag (x is int64?)
static const size_t OFF_WP   = 65792;    // 3 x [128][256] float4 packed weights

// x-dtype detector: if x is int64, all sampled high 32-bit words are zero.
__global__ void detect_x(const int* __restrict__ x, float* __restrict__ ws) {
    __shared__ int nonzero;
    if (threadIdx.x == 0) nonzero = 0;
    __syncthreads();
    if (x[2 * threadIdx.x + 1] != 0) nonzero = 1;   // benign same-value race
    __syncthreads();
    if (threadIdx.x == 0) *(int*)(ws + OFF_FLAG) = (nonzero == 0) ? 1 : 0;
}

// Pack weights as float4 per (k-quad, column): Wp[z][q][j] = {W_z[j][4q+c]}.
// Values identical to source -> FMA chains stay bit-identical.
__global__ void prep_pack(const float* __restrict__ Wi2h,
                          const float* __restrict__ Wi2o,
                          const float* __restrict__ Wo2o,
                          float* __restrict__ ws) {
    const int q = blockIdx.x;            // 0..127 (k quad)
    const int z = blockIdx.y;            // 0..2
    const int j = threadIdx.x;           // 0..255 (column)
    const float* src = (z == 0) ? Wi2h : (z == 1) ? Wi2o : Wo2o;
    const float4 v = *reinterpret_cast<const float4*>(src + (size_t)j * 512 + 4 * q);
    reinterpret_cast<float4*>(ws + OFF_WP)[((size_t)z * 128 + q) * 256 + j] = v;
}

// exact-bit wave broadcast: value of v at lane l
__device__ __forceinline__ float RLf(float v, int l) {
    return __int_as_float(__builtin_amdgcn_readlane(__float_as_int(v), l));
}

// Bit-faithful f32 scan. 256 blocks x 256 threads, 1 batch row per block;
// thread j owns column j. Register-pressure-balanced pipeline:
//   A : tokens; e staged to LDS; publish carried h.
//   B : e-part chains (k=0..255) for hn/o; e via SAME-ADDRESS b128 LDS
//       broadcast (8 FMAs per read); partials hop to LDS (aHb/aOb).
//   C : 16 sequential recurrence steps; Wi2h h-part: 56 quads in registers
//       (loaded at C entry -> live range C only) + 8 quads in LDS
//       ([8][4][256] float, lane-consecutive = conflict-free); h broadcast
//       via readlane from one distributed b128.
//   D2: o's h-part (k=256..511), readlane broadcasts, aO from aOb.
//   D : out-chains (hn part then o part), readlane broadcasts; t-ordered fold.
// Every output element's fmaf chain is the identical k-ascending sequence of
// the validated R7 kernel (f32 store/reload of partials is exact).
__global__ __launch_bounds__(256, 1) void scan_all(
    const int* __restrict__ x, const float* __restrict__ emb,
    const float* __restrict__ bih, const float* __restrict__ bio,
    const float* __restrict__ boo, float* __restrict__ ws) {
    const int j = threadIdx.x;          // column 0..255
    const int lane = j & 63;
    const int row = blockIdx.x;         // batch row
    const int mode64 = *(const int*)(ws + OFF_FLAG);

    const float4* __restrict__ Wh4  = reinterpret_cast<const float4*>(ws + OFF_WP);
    const float4* __restrict__ Wio4 = Wh4 + (size_t)128 * 256;
    const float4* __restrict__ Woo4 = Wh4 + (size_t)256 * 256;

    __shared__ __align__(16) float eW[WSTEPS][256];        // 16 KB
    __shared__ __align__(16) float hHist[WSTEPS + 1][256]; // 17 KB
    __shared__ __align__(16) float oHist[WSTEPS][256];     // 16 KB
    __shared__ float aHb[WSTEPS][256];                     // 16 KB
    __shared__ float aOb[WSTEPS][256];                     // 16 KB
    __shared__ float wTail[WTAIL][4][256];                 // 32 KB
    __shared__ int toks[WSTEPS];

    // stage Wi2h h-part tail quads (k-quads 120..127) into LDS, once
    #pragma unroll
    for (int qq = 0; qq < WTAIL; ++qq) {
        const float4 v = Wh4[(size_t)(64 + WREG + qq) * 256 + j];
        wTail[qq][0][j] = v.x; wTail[qq][1][j] = v.y;
        wTail[qq][2][j] = v.z; wTail[qq][3][j] = v.w;
    }

    const float bih_j = bih[j], bio_j = bio[j], boo_j = boo[j];

    float carry = 0.f;                  // h_0 = 0 (own column value)
    float sum = 0.f;
    __syncthreads();

    for (int w = 0; w < NWIN; ++w) {
        // ---- A: tokens; carried h; e staged to LDS
        if (j < WSTEPS) {
            const int idx = (w * WSTEPS + j) * BSZ + row;
            toks[j] = mode64 ? x[2 * idx] : x[idx];
        }
        hHist[0][j] = carry;
        __syncthreads();
        #pragma unroll
        for (int t = 0; t < WSTEPS; ++t)
            eW[t][j] = emb[(size_t)toks[t] * HD + j];
        __syncthreads();

        // ---- B: e-part chains (k = 0..255); e via same-address b128 bcast
        {
            float aH[WSTEPS], aO[WSTEPS];
            #pragma unroll
            for (int t = 0; t < WSTEPS; ++t) { aH[t] = 0.f; aO[t] = 0.f; }
            #pragma unroll 2
            for (int q = 0; q < 64; ++q) {
                const float4 wh = Wh4[(size_t)q * 256 + j];
                const float4 wo = Wio4[(size_t)q * 256 + j];
                #pragma unroll
                for (int t = 0; t < WSTEPS; ++t) {
                    const float4 e = *reinterpret_cast<const float4*>(&eW[t][4 * q]);
                    float h = aH[t], o = aO[t];
                    h = fmaf(e.x, wh.x, h); o = fmaf(e.x, wo.x, o);
                    h = fmaf(e.y, wh.y, h); o = fmaf(e.y, wo.y, o);
                    h = fmaf(e.z, wh.z, h); o = fmaf(e.z, wo.z, o);
                    h = fmaf(e.w, wh.w, h); o = fmaf(e.w, wo.w, o);
                    aH[t] = h; aO[t] = o;
                }
            }
            #pragma unroll
            for (int t = 0; t < WSTEPS; ++t) {
                aHb[t][j] = aH[t];        // own slot: exact f32 hop
                aOb[t][j] = aO[t];
            }
        }

        // ---- C: 16 sequential steps; 56 reg quads + 8 LDS quads
        {
            float4 whr[WREG];
            #pragma unroll
            for (int qq = 0; qq < WREG; ++qq)
                whr[qq] = Wh4[(size_t)(64 + qq) * 256 + j];

            for (int t = 0; t < WSTEPS; ++t) {
                __syncthreads();          // hHist[t] complete
                const float4 h4 = *reinterpret_cast<const float4*>(&hHist[t][4 * lane]);
                float ah = aHb[t][j];
                #pragma unroll
                for (int qq = 0; qq < WREG; ++qq) {
                    ah = fmaf(RLf(h4.x, qq), whr[qq].x, ah);
                    ah = fmaf(RLf(h4.y, qq), whr[qq].y, ah);
                    ah = fmaf(RLf(h4.z, qq), whr[qq].z, ah);
                    ah = fmaf(RLf(h4.w, qq), whr[qq].w, ah);
                }
                #pragma unroll
                for (int qq = 0; qq < WTAIL; ++qq) {
                    const int l = WREG + qq;
                    ah = fmaf(RLf(h4.x, l), wTail[qq][0][j], ah);
                    ah = fmaf(RLf(h4.y, l), wTail[qq][1][j], ah);
                    ah = fmaf(RLf(h4.z, l), wTail[qq][2][j], ah);
                    ah = fmaf(RLf(h4.w, l), wTail[qq][3][j], ah);
                }
                hHist[t + 1][j] = ah + bih_j;   // + b_i2h
            }
            __syncthreads();              // all h states published
            carry = hHist[WSTEPS][j];
        }

        // ---- D2: o's h-part (k = 256..511), 2 groups of 8 t
        #pragma unroll
        for (int g = 0; g < 2; ++g) {
            float4 hv[8]; float aOr[8];
            #pragma unroll
            for (int u = 0; u < 8; ++u) {
                hv[u] = *reinterpret_cast<const float4*>(&hHist[g * 8 + u][4 * lane]);
                aOr[u] = aOb[g * 8 + u][j];
            }
            #pragma unroll 2
            for (int q = 0; q < 64; ++q) {
                const float4 w4 = Wio4[(size_t)(64 + q) * 256 + j];
                #pragma unroll
                for (int u = 0; u < 8; ++u) {
                    float s;
                    s = RLf(hv[u].x, q); aOr[u] = fmaf(s, w4.x, aOr[u]);
                    s = RLf(hv[u].y, q); aOr[u] = fmaf(s, w4.y, aOr[u]);
                    s = RLf(hv[u].z, q); aOr[u] = fmaf(s, w4.z, aOr[u]);
                    s = RLf(hv[u].w, q); aOr[u] = fmaf(s, w4.w, aOr[u]);
                }
            }
            #pragma unroll
            for (int u = 0; u < 8; ++u)
                oHist[g * 8 + u][j] = aOr[u] + bio_j;    // + b_i2o
        }
        __syncthreads();                 // o published

        // ---- D: out-chains (hn part k=0..255, then o part k=256..511)
        {
            float a2[WSTEPS];
            #pragma unroll
            for (int t = 0; t < WSTEPS; ++t) a2[t] = 0.f;
            #pragma unroll
            for (int g = 0; g < 2; ++g) {
                float4 hv[8];
                #pragma unroll
                for (int u = 0; u < 8; ++u)
                    hv[u] = *reinterpret_cast<const float4*>(&hHist[g * 8 + u + 1][4 * lane]);
                #pragma unroll 2
                for (int q = 0; q < 64; ++q) {
                    const float4 w4 = Woo4[(size_t)q * 256 + j];
                    #pragma unroll
                    for (int u = 0; u < 8; ++u) {
                        const int t = g * 8 + u;
                        float s;
                        s = RLf(hv[u].x, q); a2[t] = fmaf(s, w4.x, a2[t]);
                        s = RLf(hv[u].y, q); a2[t] = fmaf(s, w4.y, a2[t]);
                        s = RLf(hv[u].z, q); a2[t] = fmaf(s, w4.z, a2[t]);
                        s = RLf(hv[u].w, q); a2[t] = fmaf(s, w4.w, a2[t]);
                    }
                }
                float4 ov[8];
                #pragma unroll
                for (int u = 0; u < 8; ++u)
                    ov[u] = *reinterpret_cast<const float4*>(&oHist[g * 8 + u][4 * lane]);
                #pragma unroll 2
                for (int q = 0; q < 64; ++q) {
                    const float4 w4 = Woo4[(size_t)(64 + q) * 256 + j];
                    #pragma unroll
                    for (int u = 0; u < 8; ++u) {
                        const int t = g * 8 + u;
                        float s;
                        s = RLf(ov[u].x, q); a2[t] = fmaf(s, w4.x, a2[t]);
                        s = RLf(ov[u].y, q); a2[t] = fmaf(s, w4.y, a2[t]);
                        s = RLf(ov[u].z, q); a2[t] = fmaf(s, w4.z, a2[t]);
                        s = RLf(ov[u].w, q); a2[t] = fmaf(s, w4.w, a2[t]);
                    }
                }
            }
            // t-ordered fold (np.mean axis-0 order), + b_oo per element
            #pragma unroll
            for (int t = 0; t < WSTEPS; ++t) sum += (a2[t] + boo_j);
        }
        // next A's writes (toks, hHist[0], eW-after-barrier) are disjoint
        // from D's reads (hHist[1..16], oHist); A's barrier gates the rest.
    }

    ws[OFF_SUM + (size_t)row * 256 + j] = sum;
}

// encoded = Sum/1024 (exact); logits = seq-k FMA + b_pred; log_softmax with
// f64-CR exp/log; first-index argmax over f32 lp.
__global__ __launch_bounds__(64) void final_k(
    const float* __restrict__ Wpred, const float* __restrict__ bpred,
    const float* __restrict__ ws, float* __restrict__ out) {
    const int b = blockIdx.x, o = threadIdx.x;
    __shared__ float enc[256];
    __shared__ float exs[64];
    __shared__ float s32s;

    #pragma unroll
    for (int u = 0; u < 4; ++u)
        enc[o * 4 + u] = ws[OFF_SUM + (size_t)b * 256 + o * 4 + u] * (1.0f / 1024.0f);
    __syncthreads();

    float acc = 0.f;
    for (int e = 0; e < 256; ++e)
        acc = fmaf(enc[e], Wpred[(size_t)o * 256 + e], acc);
    acc += bpred[o];                      // logits[b][o], f32

    float m = acc;
    #pragma unroll
    for (int d = 1; d < 64; d <<= 1) m = fmaxf(m, __shfl_xor(m, d));
    const float sh = acc - m;
    const float ex = (float)exp((double)sh);
    exs[o] = ex;
    __syncthreads();
    if (o == 0) {
        double sd = 0.0;
        for (int i = 0; i < 64; ++i) sd += (double)exs[i];
        s32s = (float)sd;
    }
    __syncthreads();
    const float log_s = (float)log((double)s32s);
    const float lp = sh - log_s;
    const float pr = (float)exp((double)lp);

    float av = lp; int ai = o;
    #pragma unroll
    for (int d = 1; d < 64; d <<= 1) {
        const float ov = __shfl_xor(av, d);
        const int oi = __shfl_xor(ai, d);
        if (ov > av || (ov == av && oi < ai)) { av = ov; ai = oi; }
    }

    out[BSZ + (size_t)b * OUTC + o] = lp;              // logprobs
    out[BSZ + 16384 + (size_t)b * OUTC + o] = pr;      // probs
    if (o == 0) out[b] = (float)ai;                    // preds
}

// ---------------- host ----------------
extern "C" void kernel_launch(void* const* d_in, const int* in_sizes, int n_in,
                              void* d_out, int out_size, void* d_ws, size_t ws_size,
                              hipStream_t stream) {
    const int*   x     = (const int*)d_in[0];
    const float* emb   = (const float*)d_in[1];
    const float* Wi2h  = (const float*)d_in[2];
    const float* b_ih  = (const float*)d_in[3];
    const float* Wi2o  = (const float*)d_in[4];
    const float* b_io  = (const float*)d_in[5];
    const float* Wo2o  = (const float*)d_in[6];
    const float* b_oo  = (const float*)d_in[7];
    const float* Wpred = (const float*)d_in[8];
    const float* b_p   = (const float*)d_in[9];
    float* ws  = (float*)d_ws;
    float* out = (float*)d_out;

    detect_x<<<1, 256, 0, stream>>>(x, ws);
    prep_pack<<<dim3(128, 3), 256, 0, stream>>>(Wi2h, Wi2o, Wo2o, ws);
    scan_all<<<dim3(256), 256, 0, stream>>>(x, emb, b_ih, b_io, b_oo, ws);
    final_k<<<dim3(256), 64, 0, stream>>>(Wpred, b_p, ws, out);
}